// Round 3
// baseline (312.556 us; speedup 1.0000x reference)
//
#include <hip/hip_runtime.h>
#include <hip/hip_bf16.h>

// VoxelGrid: 10M events -> (10, 720, 1280) fp32 grid, bilinear splat in time.
// R1: naive 20M device atomics -> 21 G atomics/s (958 us).
// R2-R4: 720-bucket sort: partial-line L2 evictions -> 4-5x write amp ~190 us.
// R5: 240 coarse buckets (y/3): write amp fixed, total 415.
// R6/R7: p3 invariant ~122 us under residency/decode/bank changes.
// R8: removing p2's register-batched scatter REGRESSED p2 (122->143).
// R9: p2 = R7 (proven 122). p3 = R7 + MLP4 uint4 loads (118.6).
// R10: polarity split: occupancy 41->63% but p3 only 118.6->115.8 -> p3 is
//   LDS-atomic-MESSAGE throughput bound (~3.3 cyc/msg/CU), not latency.
// R11: ONE packed ds_add_u32 per event (16-bit fixed point, bin-parity A/B
//   words) -> p3 ~116 -> ~40 us. Model CONFIRMED. Total 395 -> 310.
// R12: apply the same model to p2 (now the wall at ~112 us = 20M LDS atomics
//   x 3.3cyc/256CU = 107 us):
//   (a) pass A's atomicAdd(&hist[g]) RETURN VALUE is the slot index ->
//       memoize (j<<8)|g, pass B becomes a pure store. 20M -> 10M messages.
//   (b) VGPR_Count was 52 with wk[40]+gk[40] live across the barrier ->
//       arrays were in scratch (~160MB hidden traffic). __launch_bounds__
//       (1024,4) legalizes 128 VGPRs so they live in registers.

#define NUM_BINS 5
#define DT_OFFSET 1
#define GW 1280
#define GH 720
#define NSLAB (NUM_BINS * 2)   // 10 (bin, polarity) slabs in the OUTPUT
#define NGRP 240               // coarse buckets (y/3)
#define NB2 256                // phase-2 blocks
#define ITERS 40               // events per thread in p2 (256*1024*40 >= 10M)
#define GWP (GW + 4)           // padded x-stride in p3 tile
#define CURSOR_BYTES 4096      // cursor[0..239] buckets, cursor[240] overflow
#define OF_RESERVE (512*1024)  // overflow list reserve at ws tail
#define MIN_CAPG 45056         // slots/bucket (mean ~43.7K incl pad, +6 sigma)
#define FXS 8192.0f            // fixed-point scale (2^13)

// Packed record: [q:16 | ylo:2 | pos:1 | xi:11], tn ~= q/65535, y = 3*g + ylo.
// Zero word decodes to tn=0 -> contributes +0.0 (pad slots are harmless).

// ---------------- Phase 2: bucket events by y/3 (single global read) --------
__global__ __launch_bounds__(1024, 4) void p2_bucket(
        const float4* __restrict__ ev, int n,
        unsigned* __restrict__ cursor, unsigned* __restrict__ bucket,
        unsigned* __restrict__ oflist, int ofcap, int capg,
        const int* __restrict__ ct_p, const int* __restrict__ dt_p) {
    __shared__ unsigned hist[NGRP];
    __shared__ unsigned base[NGRP];

    const int chunk = (n + gridDim.x - 1) / gridDim.x;
    const int start = blockIdx.x * chunk;
    const int end   = min(n, start + chunk);

    if (threadIdx.x < NGRP) hist[threadIdx.x] = 0u;
    __syncthreads();

    const int ct  = *ct_p;
    const int dti = *dt_p;
    const float bt  = (float)(ct - dti);
    const float dtf = (float)(dti + DT_OFFSET);

    // pass A: coalesced float4 read, decode into REGISTER arrays.
    // The hist atomic's RETURN VALUE is this event's slot within the
    // block's g-run -> memoized, so pass B needs no atomic at all.
    unsigned wk[ITERS];   // packed record
    int      gj[ITERS];   // (j << 8) | g, -1 = invalid
    #pragma unroll
    for (int k = 0; k < ITERS; ++k) {
        int i = start + (int)threadIdx.x + k * 1024;
        gj[k] = -1;
        wk[k] = 0u;
        if (i < end) {
            float4 e = ev[i];
            int yi  = (int)e.z;
            int xi  = (int)e.y;
            int pos = (e.w > 0.0f) ? 1 : 0;
            int g   = yi / 3;
            int ylo = yi - 3 * g;
            float tn = (e.x - bt) / dtf;           // in [0, 1)
            unsigned q = (unsigned)(tn * 65535.0f + 0.5f);
            if (q > 65535u) q = 65535u;
            wk[k] = (q << 14) | ((unsigned)ylo << 12)
                  | ((unsigned)pos << 11) | (unsigned)xi;
            unsigned j = atomicAdd(&hist[g], 1u);  // j = slot in block's g-run
            gj[k] = (int)((j << 8) | (unsigned)g);
        }
    }
    __syncthreads();

    // reserve 64B-aligned runs in the global bucket; zero pad slots
    if (threadIdx.x < NGRP) {
        unsigned k = threadIdx.x;
        unsigned c = hist[k];
        if (c) {
            unsigned r = (c + 15u) & ~15u;
            unsigned b = atomicAdd(&cursor[k], r);
            base[k] = b;
            unsigned* bk = bucket + (size_t)k * capg;
            for (unsigned j = c; j < r; ++j) {
                unsigned slot = b + j;
                if (slot < (unsigned)capg) bk[slot] = 0u;
            }
        } else {
            base[k] = 0u;
        }
    }
    __syncthreads();

    // pass B: pure store from registers (no atomics, no re-read, no re-decode)
    #pragma unroll
    for (int k = 0; k < ITERS; ++k) {
        if (gj[k] >= 0) {
            int      g = gj[k] & 255;
            unsigned j = (unsigned)gj[k] >> 8;
            unsigned slot = base[g] + j;
            if (slot < (unsigned)capg) {
                bucket[(size_t)g * capg + slot] = wk[k];
            } else {
                unsigned o = atomicAdd(&cursor[NGRP], 1u);
                if (o < (unsigned)ofcap) {
                    oflist[2 * o]     = (unsigned)(3 * g + ((wk[k] >> 12) & 3u));
                    oflist[2 * o + 1] = wk[k];
                }
            }
        }
    }
}

// ---------------- Phase 3: two blocks per bucket (one per polarity) ---------
// Tile: per cell (ylo, x) 4 u32 words (bin-parity packed pairs, see header).
// ONE ds_add_u32 per event (was two ds_add_f32).
__device__ __forceinline__ void p3_process(unsigned w, unsigned mypos,
                                           unsigned* tile) {
    if (w == 0u) return;                       // pad (or exact-zero event)
    if (((w >> 11) & 1u) != mypos) return;     // other polarity's block
    int   xi  = (int)(w & 0x7FFu);
    int   ylo = (int)((w >> 12) & 3u);
    float qf  = (float)(w >> 14);
    float tn  = qf * (1.0f / 65535.0f);
    float bf  = qf * (4.0f / 65535.0f);
    float back = floorf(bf);
    float fw   = bf - back;
    int   b    = (int)back;
    if (b > NUM_BINS - 2) b = NUM_BINS - 2;    // q=65535 edge, same as float ver
    unsigned ql = (unsigned)((1.0f - fw) * tn * FXS + 0.5f);   // bin b
    unsigned qh = (unsigned)(fw * tn * FXS + 0.5f);            // bin b+1
    int   k   = ((b & 1) << 1) | (b >> 1);     // A0,A1,B0,B1 word select
    int   idx = (ylo * GWP + xi) * 4 + k;
    atomicAdd(&tile[idx], ql | (qh << 16));    // single ds_add_u32
}

__global__ __launch_bounds__(1024) void p3_accum(
        const unsigned* __restrict__ cursor, const unsigned* __restrict__ bucket,
        float* __restrict__ out, int capg) {
    __shared__ unsigned tile[3 * GWP * 4];     // 61,632 B (2 blocks/CU)
    // pair (g, g+NGRP) -> same XCD under round-robin dispatch (240 % 8 == 0)
    const int      g     = blockIdx.x % NGRP;
    const unsigned mypos = (unsigned)(blockIdx.x / NGRP);

    for (int k = threadIdx.x; k < 3 * GWP * 4; k += blockDim.x)
        tile[k] = 0u;
    __syncthreads();

    unsigned cnt = cursor[g];
    if (cnt > (unsigned)capg) cnt = (unsigned)capg;   // rest went to overflow
    const uint4* bk4 = (const uint4*)(bucket + (size_t)g * capg);
    unsigned n4 = cnt / 4;                            // cnt is multiple of 16

    // batch 4 independent uint4 loads per outer iteration (MLP 4x):
    const uint4 z4 = make_uint4(0u, 0u, 0u, 0u);
    for (unsigned j0 = threadIdx.x; j0 < n4; j0 += 4u * 1024u) {
        unsigned j1 = j0 + 1024u, j2 = j0 + 2048u, j3 = j0 + 3072u;
        uint4 a = bk4[j0];
        uint4 b = (j1 < n4) ? bk4[j1] : z4;
        uint4 c = (j2 < n4) ? bk4[j2] : z4;
        uint4 d = (j3 < n4) ? bk4[j3] : z4;
        p3_process(a.x, mypos, tile); p3_process(a.y, mypos, tile);
        p3_process(a.z, mypos, tile); p3_process(a.w, mypos, tile);
        p3_process(b.x, mypos, tile); p3_process(b.y, mypos, tile);
        p3_process(b.z, mypos, tile); p3_process(b.w, mypos, tile);
        p3_process(c.x, mypos, tile); p3_process(c.y, mypos, tile);
        p3_process(c.z, mypos, tile); p3_process(c.w, mypos, tile);
        p3_process(d.x, mypos, tile); p3_process(d.y, mypos, tile);
        p3_process(d.z, mypos, tile); p3_process(d.w, mypos, tile);
    }
    __syncthreads();

    // writeout: per output float4, gather 4 cells, sum u16 halves, rescale
    for (int k = threadIdx.x; k < NUM_BINS * 3 * (GW / 4); k += blockDim.x) {
        int r   = k / (GW / 4);       // 0..14 = b*3 + ylo
        int x4  = k % (GW / 4);
        int b   = r / 3;
        int ylo = r - 3 * b;
        int y   = 3 * g + ylo;
        float4 o;
        float* po = (float*)&o;
        #pragma unroll
        for (int j = 0; j < 4; ++j) {
            int cidx = ylo * GWP + (x4 * 4 + j);
            uint4 wv = *(const uint4*)&tile[cidx * 4];
            unsigned v;
            if      (b == 0) v = (wv.x & 0xFFFFu);
            else if (b == 1) v = (wv.x >> 16) + (wv.z & 0xFFFFu);
            else if (b == 2) v = (wv.y & 0xFFFFu) + (wv.z >> 16);
            else if (b == 3) v = (wv.y >> 16) + (wv.w & 0xFFFFu);
            else             v = (wv.w >> 16);
            po[j] = (float)v * (1.0f / FXS);
        }
        ((float4*)(out + ((size_t)(b * 2 + (int)mypos) * GH + y) * GW))[x4] = o;
    }
}

// ---------------- Phase 4: drain overflow list (usually empty) --------------
__global__ void p4_overflow(const unsigned* __restrict__ cursor,
                            const unsigned* __restrict__ oflist, int ofcap,
                            float* __restrict__ out) {
    unsigned nof = cursor[NGRP];
    if (nof > (unsigned)ofcap) nof = (unsigned)ofcap;
    for (unsigned k = blockIdx.x * blockDim.x + threadIdx.x; k < nof;
         k += gridDim.x * blockDim.x) {
        unsigned yi = oflist[2 * k];
        unsigned w  = oflist[2 * k + 1];
        int   xi  = (int)(w & 0x7FFu);
        int   pos = (int)((w >> 11) & 1u);
        float tn  = (float)(w >> 14) * (1.0f / 65535.0f);
        float bf  = (NUM_BINS - 1.0f) * tn;
        float back = floorf(bf);
        float fw   = bf - back;
        int   b    = (int)back;
        if (b > NUM_BINS - 2) b = NUM_BINS - 2;
        atomicAdd(&out[((size_t)(b * 2 + pos) * GH + yi) * GW + xi],
                  (1.0f - fw) * tn);
        atomicAdd(&out[((size_t)((b + 1) * 2 + pos) * GH + yi) * GW + xi],
                  fw * tn);
    }
}

// ---------------- Fallback: R1 naive atomic kernel (if ws too small) --------
__global__ void voxel_scatter_kernel(const float4* __restrict__ events,
                                     float* __restrict__ out, int n,
                                     const int* __restrict__ ct_p,
                                     const int* __restrict__ dt_p,
                                     const int* __restrict__ w_p,
                                     const int* __restrict__ h_p) {
    int i = blockIdx.x * blockDim.x + threadIdx.x;
    if (i >= n) return;
    const int ct = *ct_p, dti = *dt_p, W = *w_p, H = *h_p;
    const float bt  = (float)(ct - dti);
    const float dtf = (float)(dti + DT_OFFSET);
    float4 e = events[i];
    const float tn    = (e.x - bt) / dtf;
    const float bin_f = (NUM_BINS - 1.0f) * tn;
    const float back  = floorf(bin_f);
    const float fwd_w = bin_f - back;
    const int back_i = (int)back;
    const int pos    = (e.w > 0.0f) ? 1 : 0;
    const int xi = (int)e.y, yi = (int)e.z;
    const int plane = H * W, slab = 2 * plane;
    const int base = (back_i * 2 + pos) * plane + yi * W + xi;
    atomicAdd(&out[base],        (1.0f - fwd_w) * tn);
    atomicAdd(&out[base + slab], fwd_w * tn);
}

extern "C" void kernel_launch(void* const* d_in, const int* in_sizes, int n_in,
                              void* d_out, int out_size, void* d_ws, size_t ws_size,
                              hipStream_t stream) {
    const float4* events = (const float4*)d_in[0];
    const int* curr_time = (const int*)d_in[1];
    const int* delta_t   = (const int*)d_in[2];
    const int* width     = (const int*)d_in[3];
    const int* height    = (const int*)d_in[4];
    float* out = (float*)d_out;
    const int n = in_sizes[0] / 4;

    // ws layout: [cursor 4KB][bucket NGRP*capg*4B][overflow list (rest)]
    int capg = 0;
    if (ws_size > CURSOR_BYTES + OF_RESERVE)
        capg = (int)(((ws_size - CURSOR_BYTES - OF_RESERVE)
                      / (NGRP * sizeof(unsigned))) & ~(size_t)15);

    if (capg >= MIN_CAPG && n <= NB2 * 1024 * ITERS) {
        unsigned* cursor = (unsigned*)d_ws;
        unsigned* bucket = (unsigned*)((char*)d_ws + CURSOR_BYTES);
        unsigned* oflist = bucket + (size_t)NGRP * capg;
        int ofcap = (int)((ws_size - CURSOR_BYTES
                           - (size_t)NGRP * capg * sizeof(unsigned))
                          / (2 * sizeof(unsigned)));
        hipMemsetAsync(cursor, 0, CURSOR_BYTES, stream);
        p2_bucket<<<NB2, 1024, 0, stream>>>(events, n, cursor, bucket,
                                            oflist, ofcap, capg,
                                            curr_time, delta_t);
        p3_accum<<<2 * NGRP, 1024, 0, stream>>>(cursor, bucket, out, capg);
        p4_overflow<<<64, 256, 0, stream>>>(cursor, oflist, ofcap, out);
    } else {
        hipMemsetAsync(out, 0, (size_t)out_size * sizeof(float), stream);
        const int block = 256;
        const int grid  = (n + block - 1) / block;
        voxel_scatter_kernel<<<grid, block, 0, stream>>>(events, n ? out : out, n,
                                                         curr_time, delta_t,
                                                         width, height);
    }
}

// Round 4
// 309.236 us; speedup vs baseline: 1.0107x; 1.0107x over previous
//
#include <hip/hip_runtime.h>
#include <hip/hip_bf16.h>

// VoxelGrid: 10M events -> (10, 720, 1280) fp32 grid, bilinear splat in time.
// R1: naive 20M device atomics -> 21 G atomics/s (958 us).
// R2-R4: 720-bucket sort: partial-line L2 evictions -> 4-5x write amp ~190 us.
// R5: 240 coarse buckets (y/3): write amp fixed, total 415.
// R6-R9: p3 ~118 (MLP4), p2 ~112 (register-batched 2-pass).
// R10: polarity split: p3 118.6->115.8 only -> p3 is LDS-atomic-MESSAGE
//   throughput bound (~3.3 cyc/msg/CU), not latency.
// R11: ONE packed ds_add_u32 per event (16b fixed point, bin-parity words)
//   -> p3 ~116 -> ~40 us. Model CONFIRMED. Total 395 -> 310.
// R12: memoized hist-return j (20M->10M LDS msgs) + launch_bounds: p2
//   UNCHANGED (115) and WRITE 57->150MB, VGPR stuck at 52 -> wk[40]/gj[40]
//   live in SCRATCH (j from atomic return can't be rematerialized; 84MB
//   round-trip). p2 is NOT atomic-bound; it's scratch-traffic/latency bound.
// R13: chunk p2 into 5 chunks x 8 events/thread so staging fits registers
//   (wk[8]+gj[8]); exact unpadded runs (no pad zeroing); prefetch next
//   chunk's events under the store pass; p3 gains a scalar tail loop
//   (cnt no longer multiple of 16).

#define NUM_BINS 5
#define DT_OFFSET 1
#define GW 1280
#define GH 720
#define NSLAB (NUM_BINS * 2)   // 10 (bin, polarity) slabs in the OUTPUT
#define NGRP 240               // coarse buckets (y/3)
#define NB2 256                // phase-2 blocks
#define CH 5                   // chunks per block
#define EPT 8                  // events per thread per chunk
#define ITERS (CH * EPT)       // 40 events/thread total (capacity guard)
#define GWP (GW + 4)           // padded x-stride in p3 tile
#define CURSOR_BYTES 4096      // cursor[0..239] buckets, cursor[240] overflow
#define OF_RESERVE (512*1024)  // overflow list reserve at ws tail
#define MIN_CAPG 45056         // slots/bucket; exact counts mean 41.7K (+16s)
#define FXS 8192.0f            // fixed-point scale (2^13)

// Packed record: [q:16 | ylo:2 | pos:1 | xi:11], tn ~= q/65535, y = 3*g + ylo.

// ---------------- Phase 2: bucket events by y/3 (chunked two-pass) ----------
__global__ __launch_bounds__(1024) void p2_bucket(
        const float4* __restrict__ ev, int n,
        unsigned* __restrict__ cursor, unsigned* __restrict__ bucket,
        unsigned* __restrict__ oflist, int ofcap, int capg,
        const int* __restrict__ ct_p, const int* __restrict__ dt_p) {
    __shared__ unsigned hist[NGRP];
    __shared__ unsigned base[NGRP];

    const int chunk = (n + gridDim.x - 1) / gridDim.x;
    const int start = blockIdx.x * chunk;
    const int end   = min(n, start + chunk);
    const int tid   = (int)threadIdx.x;

    if (tid < NGRP) hist[tid] = 0u;
    __syncthreads();

    const int ct  = *ct_p;
    const int dti = *dt_p;
    const float bt  = (float)(ct - dti);
    const float dtf = (float)(dti + DT_OFFSET);

    // prologue: load chunk 0's events
    float4 e[EPT];
    #pragma unroll
    for (int k = 0; k < EPT; ++k) {
        int i = start + tid + k * 1024;
        if (i < end) e[k] = ev[i];
    }

    for (int c = 0; c < CH; ++c) {
        // pass A: decode (registers only), count via hist atomic (memoize j)
        unsigned wk[EPT];
        int      gj[EPT];   // (j << 8) | g, -1 = invalid
        #pragma unroll
        for (int k = 0; k < EPT; ++k) {
            int i = start + tid + (c * EPT + k) * 1024;
            gj[k] = -1;
            if (i < end) {
                float4 ee = e[k];
                int yi  = (int)ee.z;
                int xi  = (int)ee.y;
                int pos = (ee.w > 0.0f) ? 1 : 0;
                int g   = yi / 3;
                int ylo = yi - 3 * g;
                float tn = (ee.x - bt) / dtf;          // in [0, 1)
                unsigned q = (unsigned)(tn * 65535.0f + 0.5f);
                if (q > 65535u) q = 65535u;
                wk[k] = (q << 14) | ((unsigned)ylo << 12)
                      | ((unsigned)pos << 11) | (unsigned)xi;
                unsigned j = atomicAdd(&hist[g], 1u);
                gj[k] = (int)((j << 8) | (unsigned)g);
            }
        }
        __syncthreads();

        // reserve EXACT runs (no padding, no zeroing); reset hist for next
        if (tid < NGRP) {
            unsigned cc = hist[tid];
            if (cc) base[tid] = atomicAdd(&cursor[tid], cc);
            hist[tid] = 0u;
        }
        __syncthreads();

        // prefetch next chunk's events (latency hides under the stores)
        if (c + 1 < CH) {
            #pragma unroll
            for (int k = 0; k < EPT; ++k) {
                int i = start + tid + ((c + 1) * EPT + k) * 1024;
                if (i < end) e[k] = ev[i];
            }
        }

        // pass B: pure store from registers
        #pragma unroll
        for (int k = 0; k < EPT; ++k) {
            if (gj[k] >= 0) {
                int      g = gj[k] & 255;
                unsigned j = (unsigned)gj[k] >> 8;
                unsigned slot = base[g] + j;
                if (slot < (unsigned)capg) {
                    bucket[(size_t)g * capg + slot] = wk[k];
                } else {
                    unsigned o = atomicAdd(&cursor[NGRP], 1u);
                    if (o < (unsigned)ofcap) {
                        oflist[2 * o]     = (unsigned)(3 * g + ((wk[k] >> 12) & 3u));
                        oflist[2 * o + 1] = wk[k];
                    }
                }
            }
        }
    }
}

// ---------------- Phase 3: two blocks per bucket (one per polarity) ---------
// Tile: per cell (ylo, x) 4 u32 words (bin-parity packed pairs).
// ONE ds_add_u32 per event.
__device__ __forceinline__ void p3_process(unsigned w, unsigned mypos,
                                           unsigned* tile) {
    if (w == 0u) return;                       // exact-zero event only
    if (((w >> 11) & 1u) != mypos) return;     // other polarity's block
    int   xi  = (int)(w & 0x7FFu);
    int   ylo = (int)((w >> 12) & 3u);
    float qf  = (float)(w >> 14);
    float tn  = qf * (1.0f / 65535.0f);
    float bf  = qf * (4.0f / 65535.0f);
    float back = floorf(bf);
    float fw   = bf - back;
    int   b    = (int)back;
    if (b > NUM_BINS - 2) b = NUM_BINS - 2;
    unsigned ql = (unsigned)((1.0f - fw) * tn * FXS + 0.5f);   // bin b
    unsigned qh = (unsigned)(fw * tn * FXS + 0.5f);            // bin b+1
    int   k   = ((b & 1) << 1) | (b >> 1);     // A0,A1,B0,B1 word select
    int   idx = (ylo * GWP + xi) * 4 + k;
    atomicAdd(&tile[idx], ql | (qh << 16));    // single ds_add_u32
}

__global__ __launch_bounds__(1024) void p3_accum(
        const unsigned* __restrict__ cursor, const unsigned* __restrict__ bucket,
        float* __restrict__ out, int capg) {
    __shared__ unsigned tile[3 * GWP * 4];     // 61,632 B (2 blocks/CU)
    const int      g     = blockIdx.x % NGRP;
    const unsigned mypos = (unsigned)(blockIdx.x / NGRP);

    for (int k = threadIdx.x; k < 3 * GWP * 4; k += blockDim.x)
        tile[k] = 0u;
    __syncthreads();

    unsigned cnt = cursor[g];
    if (cnt > (unsigned)capg) cnt = (unsigned)capg;   // rest went to overflow
    const unsigned* bk = bucket + (size_t)g * capg;
    const uint4* bk4 = (const uint4*)bk;
    unsigned n4 = cnt / 4;

    // batch 4 independent uint4 loads per outer iteration (MLP 4x):
    const uint4 z4 = make_uint4(0u, 0u, 0u, 0u);
    for (unsigned j0 = threadIdx.x; j0 < n4; j0 += 4u * 1024u) {
        unsigned j1 = j0 + 1024u, j2 = j0 + 2048u, j3 = j0 + 3072u;
        uint4 a = bk4[j0];
        uint4 b = (j1 < n4) ? bk4[j1] : z4;
        uint4 c = (j2 < n4) ? bk4[j2] : z4;
        uint4 d = (j3 < n4) ? bk4[j3] : z4;
        p3_process(a.x, mypos, tile); p3_process(a.y, mypos, tile);
        p3_process(a.z, mypos, tile); p3_process(a.w, mypos, tile);
        p3_process(b.x, mypos, tile); p3_process(b.y, mypos, tile);
        p3_process(b.z, mypos, tile); p3_process(b.w, mypos, tile);
        p3_process(c.x, mypos, tile); p3_process(c.y, mypos, tile);
        p3_process(c.z, mypos, tile); p3_process(c.w, mypos, tile);
        p3_process(d.x, mypos, tile); p3_process(d.y, mypos, tile);
        p3_process(d.z, mypos, tile); p3_process(d.w, mypos, tile);
    }
    // scalar tail: cnt is no longer a multiple of 16
    for (unsigned j = n4 * 4 + threadIdx.x; j < cnt; j += 1024)
        p3_process(bk[j], mypos, tile);
    __syncthreads();

    // writeout: per output float4, gather 4 cells, sum u16 halves, rescale
    for (int k = threadIdx.x; k < NUM_BINS * 3 * (GW / 4); k += blockDim.x) {
        int r   = k / (GW / 4);       // 0..14 = b*3 + ylo
        int x4  = k % (GW / 4);
        int b   = r / 3;
        int ylo = r - 3 * b;
        int y   = 3 * g + ylo;
        float4 o;
        float* po = (float*)&o;
        #pragma unroll
        for (int j = 0; j < 4; ++j) {
            int cidx = ylo * GWP + (x4 * 4 + j);
            uint4 wv = *(const uint4*)&tile[cidx * 4];
            unsigned v;
            if      (b == 0) v = (wv.x & 0xFFFFu);
            else if (b == 1) v = (wv.x >> 16) + (wv.z & 0xFFFFu);
            else if (b == 2) v = (wv.y & 0xFFFFu) + (wv.z >> 16);
            else if (b == 3) v = (wv.y >> 16) + (wv.w & 0xFFFFu);
            else             v = (wv.w >> 16);
            po[j] = (float)v * (1.0f / FXS);
        }
        ((float4*)(out + ((size_t)(b * 2 + (int)mypos) * GH + y) * GW))[x4] = o;
    }
}

// ---------------- Phase 4: drain overflow list (usually empty) --------------
__global__ void p4_overflow(const unsigned* __restrict__ cursor,
                            const unsigned* __restrict__ oflist, int ofcap,
                            float* __restrict__ out) {
    unsigned nof = cursor[NGRP];
    if (nof > (unsigned)ofcap) nof = (unsigned)ofcap;
    for (unsigned k = blockIdx.x * blockDim.x + threadIdx.x; k < nof;
         k += gridDim.x * blockDim.x) {
        unsigned yi = oflist[2 * k];
        unsigned w  = oflist[2 * k + 1];
        int   xi  = (int)(w & 0x7FFu);
        int   pos = (int)((w >> 11) & 1u);
        float tn  = (float)(w >> 14) * (1.0f / 65535.0f);
        float bf  = (NUM_BINS - 1.0f) * tn;
        float back = floorf(bf);
        float fw   = bf - back;
        int   b    = (int)back;
        if (b > NUM_BINS - 2) b = NUM_BINS - 2;
        atomicAdd(&out[((size_t)(b * 2 + pos) * GH + yi) * GW + xi],
                  (1.0f - fw) * tn);
        atomicAdd(&out[((size_t)((b + 1) * 2 + pos) * GH + yi) * GW + xi],
                  fw * tn);
    }
}

// ---------------- Fallback: R1 naive atomic kernel (if ws too small) --------
__global__ void voxel_scatter_kernel(const float4* __restrict__ events,
                                     float* __restrict__ out, int n,
                                     const int* __restrict__ ct_p,
                                     const int* __restrict__ dt_p,
                                     const int* __restrict__ w_p,
                                     const int* __restrict__ h_p) {
    int i = blockIdx.x * blockDim.x + threadIdx.x;
    if (i >= n) return;
    const int ct = *ct_p, dti = *dt_p, W = *w_p, H = *h_p;
    const float bt  = (float)(ct - dti);
    const float dtf = (float)(dti + DT_OFFSET);
    float4 e = events[i];
    const float tn    = (e.x - bt) / dtf;
    const float bin_f = (NUM_BINS - 1.0f) * tn;
    const float back  = floorf(bin_f);
    const float fwd_w = bin_f - back;
    const int back_i = (int)back;
    const int pos    = (e.w > 0.0f) ? 1 : 0;
    const int xi = (int)e.y, yi = (int)e.z;
    const int plane = H * W, slab = 2 * plane;
    const int base = (back_i * 2 + pos) * plane + yi * W + xi;
    atomicAdd(&out[base],        (1.0f - fwd_w) * tn);
    atomicAdd(&out[base + slab], fwd_w * tn);
}

extern "C" void kernel_launch(void* const* d_in, const int* in_sizes, int n_in,
                              void* d_out, int out_size, void* d_ws, size_t ws_size,
                              hipStream_t stream) {
    const float4* events = (const float4*)d_in[0];
    const int* curr_time = (const int*)d_in[1];
    const int* delta_t   = (const int*)d_in[2];
    const int* width     = (const int*)d_in[3];
    const int* height    = (const int*)d_in[4];
    float* out = (float*)d_out;
    const int n = in_sizes[0] / 4;

    // ws layout: [cursor 4KB][bucket NGRP*capg*4B][overflow list (rest)]
    int capg = 0;
    if (ws_size > CURSOR_BYTES + OF_RESERVE)
        capg = (int)(((ws_size - CURSOR_BYTES - OF_RESERVE)
                      / (NGRP * sizeof(unsigned))) & ~(size_t)15);

    if (capg >= MIN_CAPG && n <= NB2 * 1024 * ITERS) {
        unsigned* cursor = (unsigned*)d_ws;
        unsigned* bucket = (unsigned*)((char*)d_ws + CURSOR_BYTES);
        unsigned* oflist = bucket + (size_t)NGRP * capg;
        int ofcap = (int)((ws_size - CURSOR_BYTES
                           - (size_t)NGRP * capg * sizeof(unsigned))
                          / (2 * sizeof(unsigned)));
        hipMemsetAsync(cursor, 0, CURSOR_BYTES, stream);
        p2_bucket<<<NB2, 1024, 0, stream>>>(events, n, cursor, bucket,
                                            oflist, ofcap, capg,
                                            curr_time, delta_t);
        p3_accum<<<2 * NGRP, 1024, 0, stream>>>(cursor, bucket, out, capg);
        p4_overflow<<<64, 256, 0, stream>>>(cursor, oflist, ofcap, out);
    } else {
        hipMemsetAsync(out, 0, (size_t)out_size * sizeof(float), stream);
        const int block = 256;
        const int grid  = (n + block - 1) / block;
        voxel_scatter_kernel<<<grid, block, 0, stream>>>(events, out, n,
                                                         curr_time, delta_t,
                                                         width, height);
    }
}